// Round 1
// baseline (126.739 us; speedup 1.0000x reference)
//
#include <hip/hip_runtime.h>
#include <math.h>

// Problem: X[16384,64] fp32, W[8192,64] fp32 -> argmin_c ||x-w_c||^2 (int32)
#define EMB     64
#define NTOK    8192
#define NQ      16384
#define TPB     256
#define CSPLIT  4
#define CRANGE  (NTOK / CSPLIT)   // 2048 codewords per block
#define BQ      128               // query rows per block
#define TILE_C  128               // codewords staged in LDS per iteration
#define NT      (CRANGE / TILE_C) // 16 tiles per block
#define TCH     (TILE_C * EMB)    // halves per tile buffer (8192 = 16KB)

typedef _Float16 half8 __attribute__((ext_vector_type(8)));
typedef float    f32x4 __attribute__((ext_vector_type(4)));

// async global->LDS DMA, 16B per lane (dest = wave-uniform base + lane*16)
__device__ __forceinline__ void gl2lds16(const _Float16* g, _Float16* l) {
    __builtin_amdgcn_global_load_lds(
        (const __attribute__((address_space(1))) unsigned int*)g,
        (__attribute__((address_space(3))) unsigned int*)l, 16, 0, 0);
}

// ---------------------------------------------------------------------------
// Prep A: ||w_c||^2 in fp32
// ---------------------------------------------------------------------------
__global__ void ynorm_kernel(const float* __restrict__ W, float* __restrict__ ynorm) {
    int c = blockIdx.x * blockDim.x + threadIdx.x;
    if (c >= NTOK) return;
    const float4* w4 = (const float4*)(W + (size_t)c * EMB);
    float s = 0.f;
#pragma unroll
    for (int i = 0; i < EMB / 4; ++i) {
        float4 v = w4[i];
        s = fmaf(v.x, v.x, s); s = fmaf(v.y, v.y, s);
        s = fmaf(v.z, v.z, s); s = fmaf(v.w, v.w, s);
    }
    ynorm[c] = s;
}

// ---------------------------------------------------------------------------
// Prep B: split W into fp16 hi + fp16 lo, stored in MFMA-FRAGMENT ORDER.
// Chunk u (16B = 8 halves): u = g*128 + kb*64 + lane, lane = lq*16 + r.
// Contents: W[g*16 + r][kb*32 + lq*8 .. +7]. A wave reading group g, half kb
// reads 64 consecutive chunks -> linear global_load_lds + conflict-free
// ds_read_b128 (no padding, no swizzle on either side).
// ---------------------------------------------------------------------------
__global__ void wsplit_kernel(const float* __restrict__ W,
                              _Float16* __restrict__ Wh, _Float16* __restrict__ Wl) {
    int u = blockIdx.x * blockDim.x + threadIdx.x;   // 0 .. NTOK*8-1 (chunk id)
    int g    = u >> 7;
    int rem  = u & 127;
    int kb   = rem >> 6;
    int lane = rem & 63;
    int r    = lane & 15, lq = lane >> 4;
    int c    = g * 16 + r;
    int k0   = kb * 32 + lq * 8;
    const float* wp = W + (size_t)c * EMB + k0;
    float4 v0 = *(const float4*)wp;
    float4 v1 = *(const float4*)(wp + 4);
    float xv[8] = {v0.x, v0.y, v0.z, v0.w, v1.x, v1.y, v1.z, v1.w};
    half8 h, l;
#pragma unroll
    for (int j = 0; j < 8; ++j) {
        _Float16 hh = (_Float16)xv[j];
        h[j] = hh;
        l[j] = (_Float16)(xv[j] - (float)hh);
    }
    *(half8*)(Wh + (size_t)u * 8) = h;
    *(half8*)(Wl + (size_t)u * 8) = l;
}

// ---------------------------------------------------------------------------
// Main: fp16x4-split MFMA distance + argmin, 2-phase pipelined staging.
// Block: 4 waves = 2(q-half: 64 rows) x 2(c-half: 64 cols of the staged 128).
// Per tile: STAGE(t+1) via global_load_lds (async, 8 ops/wave) -> COMPUTE(t)
// -> s_waitcnt vmcnt(0)+lgkmcnt(0) -> raw s_barrier. DMA of tile t+1 is in
// flight underneath tile t's 128 MFMAs; no __syncthreads drain in the loop.
// Numerics identical to the verified kernel (same term order, same tie-break).
// ---------------------------------------------------------------------------
__global__ __launch_bounds__(TPB, 2) void vq_mfma_kernel(
    const float* __restrict__ X,
    const _Float16* __restrict__ Wh, const _Float16* __restrict__ Wl,
    const float* __restrict__ ynorm,
    float* __restrict__ pval, int* __restrict__ pidx)
{
    __shared__ __align__(16) _Float16 LdsH0[TCH];
    __shared__ __align__(16) _Float16 LdsH1[TCH];
    __shared__ __align__(16) _Float16 LdsL0[TCH];
    __shared__ __align__(16) _Float16 LdsL1[TCH];
    __shared__ __align__(16) float    Lyn[CRANGE];   // whole c-range ynorm (8KB)
    __shared__ float RedV[2][BQ];
    __shared__ int   RedI[2][BQ];

    const int t    = threadIdx.x;
    const int lane = t & 63;
    const int wid  = t >> 6;       // 0..3
    const int wq   = wid & 1;      // q half (0/1)
    const int wy   = wid >> 1;     // c half (0/1)
    const int l15  = lane & 15;
    const int lq   = lane >> 4;    // 0..3

    const int qblk   = blockIdx.x * BQ;
    const int qbase  = qblk + wq * 64;
    const int cbase0 = blockIdx.y * CRANGE;

    // --- issue tile-0 DMA first so it overlaps prologue work ---
    {
        const size_t gsbase = (size_t)(cbase0 >> 4) * 1024;   // halves
#pragma unroll
        for (int i = 0; i < 4; ++i) {
            const int jw = i * 256 + wid * 64;                // wave-uniform chunk base
            gl2lds16(Wh + gsbase + (size_t)(jw + lane) * 8, LdsH0 + (size_t)jw * 8);
            gl2lds16(Wl + gsbase + (size_t)(jw + lane) * 8, LdsL0 + (size_t)jw * 8);
        }
    }

    // --- stage the block's full ynorm range once ---
    for (int u = t; u < CRANGE / 4; u += TPB)
        ((float4*)Lyn)[u] = ((const float4*)(ynorm + cbase0))[u];

    // --- A fragments: X rows (qbase + mt*16 + l15), k = kb*32 + lq*8 + j ---
    half8 ah[4][2], al[4][2];
#pragma unroll
    for (int mt = 0; mt < 4; ++mt) {
#pragma unroll
        for (int kb = 0; kb < 2; ++kb) {
            const float* xp = X + (size_t)(qbase + mt * 16 + l15) * EMB + kb * 32 + lq * 8;
            float4 v0 = *(const float4*)xp;
            float4 v1 = *(const float4*)(xp + 4);
            float xv[8] = {v0.x, v0.y, v0.z, v0.w, v1.x, v1.y, v1.z, v1.w};
            half8 h, l;
#pragma unroll
            for (int j = 0; j < 8; ++j) {
                _Float16 hh = (_Float16)xv[j];
                h[j] = hh;
                l[j] = (_Float16)(xv[j] - (float)hh);
            }
            ah[mt][kb] = h;
            al[mt][kb] = l;
        }
    }

    float minv[4][4];
    int   mini[4][4];
#pragma unroll
    for (int mt = 0; mt < 4; ++mt)
#pragma unroll
        for (int r = 0; r < 4; ++r) { minv[mt][r] = INFINITY; mini[mt][r] = 0; }

    const f32x4 zero4 = {0.f, 0.f, 0.f, 0.f};

    __syncthreads();   // one-time full drain: tile0 DMA + Lyn writes visible

    int cur = 0;
    for (int tt = 0; tt < NT; ++tt) {
        // --- STAGE tile tt+1 into the other buffer (async DMA, stays in flight) ---
        if (tt + 1 < NT) {
            const size_t gsbase = (size_t)((cbase0 + (tt + 1) * TILE_C) >> 4) * 1024;
            _Float16* dH = (cur ^ 1) ? LdsH1 : LdsH0;
            _Float16* dL = (cur ^ 1) ? LdsL1 : LdsL0;
#pragma unroll
            for (int i = 0; i < 4; ++i) {
                const int jw = i * 256 + wid * 64;
                gl2lds16(Wh + gsbase + (size_t)(jw + lane) * 8, dH + (size_t)jw * 8);
                gl2lds16(Wl + gsbase + (size_t)(jw + lane) * 8, dL + (size_t)jw * 8);
            }
        }

        // --- COMPUTE tile tt from buf cur ---
        const _Float16* LH = cur ? LdsH1 : LdsH0;
        const _Float16* LL = cur ? LdsL1 : LdsL0;
        const int c0 = tt * TILE_C;
#pragma unroll
        for (int ct = 0; ct < 4; ++ct) {
            const int chunk0 = (wy * 4 + ct) * 128 + lane;   // 64 consecutive chunks/wave
            half8 bh0 = *(const half8*)(LH + (size_t)chunk0 * 8);
            half8 bl0 = *(const half8*)(LL + (size_t)chunk0 * 8);
            half8 bh1 = *(const half8*)(LH + (size_t)(chunk0 + 64) * 8);
            half8 bl1 = *(const half8*)(LL + (size_t)(chunk0 + 64) * 8);
            f32x4 acc[4];
#pragma unroll
            for (int mt = 0; mt < 4; ++mt) {
                f32x4 a = __builtin_amdgcn_mfma_f32_16x16x32_f16(al[mt][0], bl0, zero4, 0, 0, 0);
                a = __builtin_amdgcn_mfma_f32_16x16x32_f16(al[mt][0], bh0, a, 0, 0, 0);
                a = __builtin_amdgcn_mfma_f32_16x16x32_f16(ah[mt][0], bl0, a, 0, 0, 0);
                a = __builtin_amdgcn_mfma_f32_16x16x32_f16(ah[mt][0], bh0, a, 0, 0, 0);
                a = __builtin_amdgcn_mfma_f32_16x16x32_f16(al[mt][1], bl1, a, 0, 0, 0);
                a = __builtin_amdgcn_mfma_f32_16x16x32_f16(al[mt][1], bh1, a, 0, 0, 0);
                a = __builtin_amdgcn_mfma_f32_16x16x32_f16(ah[mt][1], bl1, a, 0, 0, 0);
                a = __builtin_amdgcn_mfma_f32_16x16x32_f16(ah[mt][1], bh1, a, 0, 0, 0);
                acc[mt] = a;
            }
            // --- epilogue: dist = ynorm - 2*dot; running argmin (c ascending, strict <) ---
            const int   ccol = wy * 64 + ct * 16;
            const float yn   = Lyn[c0 + ccol + l15];
            const int   cidx = cbase0 + c0 + ccol + l15;
#pragma unroll
            for (int mt = 0; mt < 4; ++mt) {
#pragma unroll
                for (int r = 0; r < 4; ++r) {
                    float s = fmaf(-2.f, acc[mt][r], yn);
                    if (s < minv[mt][r]) { minv[mt][r] = s; mini[mt][r] = cidx; }
                }
            }
        }

        // --- drain: tile tt+1 DMA has been landing under the MFMAs above ---
        asm volatile("s_waitcnt vmcnt(0)" ::: "memory");
        asm volatile("s_waitcnt lgkmcnt(0)" ::: "memory");
        __builtin_amdgcn_s_barrier();
        cur ^= 1;
    }

    // --- cross-lane: reduce over the 16 col-lanes (xor on low 4 lane bits) ---
#pragma unroll
    for (int mt = 0; mt < 4; ++mt) {
#pragma unroll
        for (int r = 0; r < 4; ++r) {
            float v = minv[mt][r];
            int   i = mini[mt][r];
#pragma unroll
            for (int m = 1; m <= 8; m <<= 1) {
                float ov = __shfl_xor(v, m, 64);
                int   oi = __shfl_xor(i, m, 64);
                if (ov < v || (ov == v && oi < i)) { v = ov; i = oi; }
            }
            if (l15 == 0) {
                int qoff = wq * 64 + mt * 16 + lq * 4 + r;   // row within block
                RedV[wy][qoff] = v;
                RedI[wy][qoff] = i;
            }
        }
    }
    __syncthreads();

    // --- combine the two c-halves, write per-split partial ---
    if (t < BQ) {
        float v0 = RedV[0][t]; int i0 = RedI[0][t];
        float v1 = RedV[1][t]; int i1 = RedI[1][t];
        if (v1 < v0 || (v1 == v0 && i1 < i0)) { v0 = v1; i0 = i1; }
        size_t o = (size_t)blockIdx.y * NQ + qblk + t;
        pval[o] = v0;
        pidx[o] = i0;
    }
}

// ---------------------------------------------------------------------------
// Combine CSPLIT partials -> final int32 indices
// ---------------------------------------------------------------------------
__global__ void combine_kernel(const float* __restrict__ pval,
                               const int* __restrict__ pidx,
                               int* __restrict__ out)
{
    int q = blockIdx.x * blockDim.x + threadIdx.x;
    if (q >= NQ) return;
    float bv = pval[q];
    int   bi = pidx[q];
#pragma unroll
    for (int s = 1; s < CSPLIT; ++s) {
        float v  = pval[(size_t)s * NQ + q];
        int   i2 = pidx[(size_t)s * NQ + q];
        if (v < bv || (v == bv && i2 < bi)) { bv = v; bi = i2; }
    }
    out[q] = bi;
}

// ---------------------------------------------------------------------------
extern "C" void kernel_launch(void* const* d_in, const int* in_sizes, int n_in,
                              void* d_out, int out_size, void* d_ws, size_t ws_size,
                              hipStream_t stream) {
    const float* X = (const float*)d_in[0];   // [16384, 64]
    const float* W = (const float*)d_in[1];   // [8192, 64]

    // ws layout: Wh(1MB) | Wl(1MB) | ynorm(32KB) | pval(256KB) | pidx(256KB)
    _Float16* Wh    = (_Float16*)d_ws;
    _Float16* Wl    = Wh + (size_t)NTOK * EMB;
    float*    ynorm = (float*)(Wl + (size_t)NTOK * EMB);
    float*    pval  = ynorm + NTOK;
    int*      pidx  = (int*)(pval + (size_t)CSPLIT * NQ);
    int*      out   = (int*)d_out;

    ynorm_kernel<<<NTOK / TPB, TPB, 0, stream>>>(W, ynorm);
    wsplit_kernel<<<(NTOK * 8) / TPB, TPB, 0, stream>>>(W, Wh, Wl);
    dim3 grid(NQ / BQ, CSPLIT);
    vq_mfma_kernel<<<grid, TPB, 0, stream>>>(X, Wh, Wl, ynorm, pval, pidx);
    combine_kernel<<<NQ / TPB, TPB, 0, stream>>>(pval, pidx, out);
}